// Round 4
// baseline (291.709 us; speedup 1.0000x reference)
//
#include <hip/hip_runtime.h>
#include <math.h>

#define C_IN   256
#define HW_    4096
#define KW_    769
#define NPIX_BN 32768.0f

typedef short bf16x8 __attribute__((ext_vector_type(8)));
typedef float f32x4  __attribute__((ext_vector_type(4)));
typedef unsigned short u16x8 __attribute__((ext_vector_type(8)));

__device__ inline unsigned short f2bf(float x){
    unsigned u = __float_as_uint(x);
    u += 0x7fffu + ((u >> 16) & 1u);      // RNE
    return (unsigned short)(u >> 16);
}
__device__ inline float bf2f(unsigned short h){
    return __uint_as_float(((unsigned)h) << 16);
}

// ---------------------------------------------------------------------------
// prep_w: w fp32 [256][769] -> wprep bf16 fragment-ordered
// chunk = ((m*8+ks)*4+kq)*256 + o, 8 k-contiguous bf16 per chunk
// ---------------------------------------------------------------------------
__global__ __launch_bounds__(256) void prep_w(
    const float* __restrict__ w, unsigned short* __restrict__ wp)
{
    int idx = blockIdx.x * 256 + threadIdx.x;     // 196608 total
    int j  = idx & 7;
    int o  = (idx >> 3) & 255;
    int t2 = idx >> 11;                           // m*32 + ks*4 + kq
    int kq = t2 & 3, ks = (t2 >> 2) & 7, m = t2 >> 5;
    int c  = m * 256 + ks * 32 + kq * 8 + j;
    wp[idx] = f2bf(w[(size_t)o * KW_ + c]);
}

// ---------------------------------------------------------------------------
// conv kernel: fp32 -> bf16 fragment-ordered staging + fused attn.
// grid 512 = b(8) x pgrp(64); 256 thr; wave g stages k-chunk kq=g.
// XF/XS layout: [(b*8+ks)*4+kq][pixel 4096] of 8 k-contiguous bf16 (16B).
// ---------------------------------------------------------------------------
__global__ __launch_bounds__(256) void conv_kernel(
    const float* __restrict__ f_s, const float* __restrict__ sfb,
    unsigned short* __restrict__ xf, unsigned short* __restrict__ xs,
    float* __restrict__ attn)
{
    __shared__ float red[4][64];
    int blk = blockIdx.x;
    int t = threadIdx.x, lane = t & 63, g = t >> 6;
    int b = blk >> 6;
    int p = (blk & 63) * 64 + lane;
    const float* fB = f_s + (size_t)b * C_IN * HW_ + p;
    const float* sB = sfb + (size_t)b * C_IN * HW_ + p;
    u16x8* XF = (u16x8*)xf;
    u16x8* XS = (u16x8*)xs;

    float ap = 0.f;
    float fv[8], sv[8], fv2[8], sv2[8];
    #pragma unroll
    for (int j = 0; j < 8; ++j) {
        fv[j] = fB[(size_t)(g * 8 + j) * HW_];
        sv[j] = sB[(size_t)(g * 8 + j) * HW_];
    }
    for (int ks = 0; ks < 8; ++ks) {
        if (ks < 7) {
            #pragma unroll
            for (int j = 0; j < 8; ++j) {
                fv2[j] = fB[(size_t)((ks + 1) * 32 + g * 8 + j) * HW_];
                sv2[j] = sB[(size_t)((ks + 1) * 32 + g * 8 + j) * HW_];
            }
        }
        u16x8 pf, ps;
        #pragma unroll
        for (int j = 0; j < 8; ++j) {
            ap += fv[j] * sv[j];
            pf[j] = f2bf(fv[j]);
            ps[j] = f2bf(sv[j]);
        }
        int plane = (b * 8 + ks) * 4 + g;
        XF[(size_t)plane * HW_ + p] = pf;
        XS[(size_t)plane * HW_ + p] = ps;
        #pragma unroll
        for (int j = 0; j < 8; ++j) { fv[j] = fv2[j]; sv[j] = sv2[j]; }
    }
    red[g][lane] = ap;
    __syncthreads();
    if (t < 64) {
        float a = red[0][t] + red[1][t] + red[2][t] + red[3][t];
        attn[blk * 64 + t] = 1.f / (1.f + __expf(-a));
    }
}

// ---------------------------------------------------------------------------
// dist kernel: ballot-compacted fg list + brute-force min distance (unrolled)
// ---------------------------------------------------------------------------
__global__ __launch_bounds__(1024) void dist_kernel(
    const float* __restrict__ mask, float* __restrict__ dist_raw,
    unsigned* __restrict__ dmax)
{
    __shared__ float2 fg[4096];
    __shared__ int cnt;
    __shared__ float wmax[16];
    int b = blockIdx.x, tile = blockIdx.y;
    int t = threadIdx.x, lane = t & 63;
    if (t == 0) cnt = 0;
    __syncthreads();
    const float* mb = mask + (size_t)b * 65536;
    #pragma unroll
    for (int r = 0; r < 4; ++r) {
        int pp = r * 1024 + t;
        int i = pp >> 6, j = pp & 63;
        bool pred = mb[i * 1024 + j * 4] > 0.5f;
        unsigned long long bal = __ballot(pred);
        int base = 0;
        if (lane == 0) base = atomicAdd(&cnt, __popcll(bal));
        base = __shfl(base, 0, 64);
        if (pred)
            fg[base + __popcll(bal & ((1ull << lane) - 1ull))] =
                make_float2((float)i, (float)j);
    }
    __syncthreads();
    int nfg = cnt;
    int pix = tile * 256 + (t >> 2);
    int q = t & 3;
    float py = (float)(pix >> 6), px = (float)(pix & 63);
    float m = 3.4e38f;
    #pragma unroll 4
    for (int it = q; it < nfg; it += 4) {
        float dy = py - fg[it].x;
        float dx = px - fg[it].y;
        m = fminf(m, dy * dy + dx * dx);
    }
    m = fminf(m, __shfl_xor(m, 1, 64));
    m = fminf(m, __shfl_xor(m, 2, 64));
    float d = (nfg == 0) ? 1.0f : sqrtf(m);
    if (q == 0) dist_raw[b * HW_ + pix] = d;
    float mm = d;
    #pragma unroll
    for (int off = 1; off < 64; off <<= 1)
        mm = fmaxf(mm, __shfl_xor(mm, off, 64));
    if (lane == 0) wmax[t >> 6] = mm;
    __syncthreads();
    if (t == 0) {
        float M = wmax[0];
        #pragma unroll
        for (int i = 1; i < 16; ++i) M = fmaxf(M, wmax[i]);
        atomicMax(dmax + b, __float_as_uint(M));
    }
}

// ---------------------------------------------------------------------------
// MFMA GEMM: barrier-free, LDS-free. B-frags direct from staged global bf16,
// A-frags from wprep (L2). 128o x 64n tile, 4 waves (64o x 32n), 3 acc groups.
// Epilogue: attn/dist combine, bf16 y store, BN partial stats.
// ---------------------------------------------------------------------------
__global__ __launch_bounds__(256) void gemm_kernel(
    const unsigned short* __restrict__ xf, const unsigned short* __restrict__ xs,
    const unsigned short* __restrict__ wprep, const float* __restrict__ w,
    const float* __restrict__ attn, const float* __restrict__ dist_raw,
    const unsigned* __restrict__ dmax,
    unsigned short* __restrict__ ybf,
    float* __restrict__ gsum, float* __restrict__ gsumsq)
{
    __shared__ float red[2][64][2];
    int bx = blockIdx.x;
    int ot = bx & 1, nt = bx >> 1;
    int oBase = ot * 128, nBase = nt * 64;
    int b = nBase >> 12, pBase = nBase & 4095;
    int t = threadIdx.x, lane = t & 63, g = t >> 6;
    int wo = g >> 1, wn = g & 1;
    int l15 = lane & 15, kq = lane >> 4;

    const bf16x8* XF = (const bf16x8*)xf;
    const bf16x8* XS = (const bf16x8*)xs;
    const bf16x8* WP = (const bf16x8*)wprep;
    int pix = pBase + wn * 32 + l15;

    f32x4 acc[3][4][2];
    #pragma unroll
    for (int m = 0; m < 3; ++m)
        #pragma unroll
        for (int fo = 0; fo < 4; ++fo)
            #pragma unroll
            for (int fn = 0; fn < 2; ++fn)
                acc[m][fo][fn] = (f32x4){0.f, 0.f, 0.f, 0.f};

    #pragma unroll 4
    for (int ks = 0; ks < 8; ++ks) {
        int plane = (b * 8 + ks) * 4 + kq;
        bf16x8 bf0 = XF[(size_t)plane * HW_ + pix];
        bf16x8 bf1 = XF[(size_t)plane * HW_ + pix + 16];
        bf16x8 bs0 = XS[(size_t)plane * HW_ + pix];
        bf16x8 bs1 = XS[(size_t)plane * HW_ + pix + 16];
        #pragma unroll
        for (int fo = 0; fo < 4; ++fo) {
            int o = oBase + wo * 64 + fo * 16 + l15;
            bf16x8 a1 = WP[((0 * 8 + ks) * 4 + kq) * 256 + o];
            bf16x8 a2 = WP[((1 * 8 + ks) * 4 + kq) * 256 + o];
            bf16x8 a3 = WP[((2 * 8 + ks) * 4 + kq) * 256 + o];
            acc[0][fo][0] = __builtin_amdgcn_mfma_f32_16x16x32_bf16(a1, bf0, acc[0][fo][0], 0, 0, 0);
            acc[0][fo][1] = __builtin_amdgcn_mfma_f32_16x16x32_bf16(a1, bf1, acc[0][fo][1], 0, 0, 0);
            acc[1][fo][0] = __builtin_amdgcn_mfma_f32_16x16x32_bf16(a2, bs0, acc[1][fo][0], 0, 0, 0);
            acc[1][fo][1] = __builtin_amdgcn_mfma_f32_16x16x32_bf16(a2, bs1, acc[1][fo][1], 0, 0, 0);
            acc[2][fo][0] = __builtin_amdgcn_mfma_f32_16x16x32_bf16(a3, bf0, acc[2][fo][0], 0, 0, 0);
            acc[2][fo][1] = __builtin_amdgcn_mfma_f32_16x16x32_bf16(a3, bf1, acc[2][fo][1], 0, 0, 0);
        }
    }

    // ---- epilogue ----
    float dinv = 1.0f / (__uint_as_float(dmax[b]) + 1e-6f);
    const float* dR = dist_raw + b * HW_ + pBase;
    const float* aR = attn + nBase;
    float at[2], dn[2];
    #pragma unroll
    for (int fn = 0; fn < 2; ++fn) {
        int nb = wn * 32 + fn * 16 + l15;
        at[fn] = aR[nb];
        dn[fn] = dR[nb] * dinv;
    }
    float s_acc[4][4], ss_acc[4][4];
    #pragma unroll
    for (int fo = 0; fo < 4; ++fo) {
        #pragma unroll
        for (int r = 0; r < 4; ++r) {
            int o = oBase + wo * 64 + fo * 16 + kq * 4 + r;
            float wd = w[(size_t)o * KW_ + 768];
            float s = 0.f, ss = 0.f;
            #pragma unroll
            for (int fn = 0; fn < 2; ++fn) {
                float v = acc[0][fo][fn][r] + acc[1][fo][fn][r]
                        + at[fn] * acc[2][fo][fn][r] + wd * dn[fn];
                int nb = wn * 32 + fn * 16 + l15;
                ybf[((size_t)b * C_IN + o) * HW_ + pBase + nb] = f2bf(v);
                s += v; ss += v * v;
            }
            s_acc[fo][r] = s; ss_acc[fo][r] = ss;
        }
    }
    #pragma unroll
    for (int m = 8; m; m >>= 1) {
        #pragma unroll
        for (int fo = 0; fo < 4; ++fo)
            #pragma unroll
            for (int r = 0; r < 4; ++r) {
                s_acc[fo][r]  += __shfl_xor(s_acc[fo][r],  m, 64);
                ss_acc[fo][r] += __shfl_xor(ss_acc[fo][r], m, 64);
            }
    }
    if (wn == 1 && l15 == 0) {
        #pragma unroll
        for (int fo = 0; fo < 4; ++fo)
            #pragma unroll
            for (int r = 0; r < 4; ++r) {
                int ol = fo * 16 + kq * 4 + r;
                red[wo][ol][0] = s_acc[fo][r];
                red[wo][ol][1] = ss_acc[fo][r];
            }
    }
    __syncthreads();
    if (wn == 0 && l15 == 0) {
        #pragma unroll
        for (int fo = 0; fo < 4; ++fo)
            #pragma unroll
            for (int r = 0; r < 4; ++r) {
                int ol = fo * 16 + kq * 4 + r;
                int o = oBase + wo * 64 + ol;
                atomicAdd(&gsum[o],   s_acc[fo][r]  + red[wo][ol][0]);
                atomicAdd(&gsumsq[o], ss_acc[fo][r] + red[wo][ol][1]);
            }
    }
}

// ---------------------------------------------------------------------------
// BN finalize + relu: read bf16 y, write fp32 out.
// ---------------------------------------------------------------------------
__global__ __launch_bounds__(256) void bn_kernel(
    const float* __restrict__ gsum, const float* __restrict__ gsumsq,
    const float* __restrict__ gamma, const float* __restrict__ beta,
    const unsigned short* __restrict__ ybf, float* __restrict__ out)
{
    int bo = blockIdx.x;
    int o = bo & 255;
    float mean = gsum[o] * (1.0f / NPIX_BN);
    float var  = gsumsq[o] * (1.0f / NPIX_BN) - mean * mean;
    float sc = gamma[o] * rsqrtf(var + 1e-5f);
    float sh = beta[o] - mean * sc;
    const u16x8* yp = (const u16x8*)(ybf + (size_t)bo * HW_);
    float4* op = (float4*)(out + (size_t)bo * HW_);
    int t = threadIdx.x;
    #pragma unroll
    for (int r = 0; r < 2; ++r) {
        u16x8 v = yp[r * 256 + t];
        float4 lo, hi;
        lo.x = fmaxf(bf2f(v[0]) * sc + sh, 0.f);
        lo.y = fmaxf(bf2f(v[1]) * sc + sh, 0.f);
        lo.z = fmaxf(bf2f(v[2]) * sc + sh, 0.f);
        lo.w = fmaxf(bf2f(v[3]) * sc + sh, 0.f);
        hi.x = fmaxf(bf2f(v[4]) * sc + sh, 0.f);
        hi.y = fmaxf(bf2f(v[5]) * sc + sh, 0.f);
        hi.z = fmaxf(bf2f(v[6]) * sc + sh, 0.f);
        hi.w = fmaxf(bf2f(v[7]) * sc + sh, 0.f);
        op[(r * 256 + t) * 2]     = lo;
        op[(r * 256 + t) * 2 + 1] = hi;
    }
}

// ---------------------------------------------------------------------------
// ws layout (float units):
//   [0,     32768)   dist_raw
//   [32768, 32776)   dmax (uint)
//   [32784, 33040)   gsum
//   [33040, 33296)   gsumsq
//   [33296, 66064)   attn
//   [66064, 164368)  wprep (196608 ushort)
//   [164608, ...)    staging:
//     P1 (ws >= ~51MB): XF (4194304 f) | XS (4194304 f) | ybf (4194304 f)
//     P2 (else):        ybf only; XF/XS live in d_out (exact 33.5MB fit,
//                       fully consumed by gemm before bn rewrites d_out)
// ---------------------------------------------------------------------------
extern "C" void kernel_launch(void* const* d_in, const int* in_sizes, int n_in,
                              void* d_out, int out_size, void* d_ws, size_t ws_size,
                              hipStream_t stream)
{
    const float* f_s   = (const float*)d_in[0];
    const float* sfb   = (const float*)d_in[1];
    const float* mask  = (const float*)d_in[2];
    const float* w     = (const float*)d_in[3];
    const float* gamma = (const float*)d_in[4];
    const float* beta  = (const float*)d_in[5];
    float* out = (float*)d_out;
    float* ws  = (float*)d_ws;

    float*          dist_raw = ws;
    unsigned*       dmax     = (unsigned*)(ws + 32768);
    float*          gsum     = ws + 32784;
    float*          gsumsq   = ws + 33040;
    float*          attn_b   = ws + 33296;
    unsigned short* wprep    = (unsigned short*)(ws + 66064);

    const size_t P1_need = ((size_t)164608 + 3 * 4194304) * 4;  // ~51 MB
    unsigned short *xf, *xs, *ybf;
    if (ws_size >= P1_need) {
        xf  = (unsigned short*)(ws + 164608);
        xs  = (unsigned short*)(ws + 164608 + 4194304);
        ybf = (unsigned short*)(ws + 164608 + 2 * (size_t)4194304);
    } else {
        xf  = (unsigned short*)d_out;
        xs  = ((unsigned short*)d_out) + 8388608;
        ybf = (unsigned short*)(ws + 164608);
    }

    hipMemsetAsync(ws + 32768, 0, (33296 - 32768) * 4, stream);

    prep_w<<<768, 256, 0, stream>>>(w, wprep);
    conv_kernel<<<512, 256, 0, stream>>>(f_s, sfb, xf, xs, attn_b);
    dist_kernel<<<dim3(8, 16), 1024, 0, stream>>>(mask, dist_raw, dmax);
    gemm_kernel<<<1024, 256, 0, stream>>>(xf, xs, wprep, w, attn_b, dist_raw,
                                          dmax, ybf, gsum, gsumsq);
    bn_kernel<<<2048, 256, 0, stream>>>(gsum, gsumsq, gamma, beta, ybf, out);
}

// Round 5
// 234.142 us; speedup vs baseline: 1.2459x; 1.2459x over previous
//
#include <hip/hip_runtime.h>
#include <math.h>

#define C_IN   256
#define HW_    4096
#define KW_    769
#define NPIX_BN 32768.0f

typedef short bf16x8 __attribute__((ext_vector_type(8)));
typedef float f32x4  __attribute__((ext_vector_type(4)));
typedef unsigned short u16x8 __attribute__((ext_vector_type(8)));

__device__ inline unsigned short f2bf(float x){
    unsigned u = __float_as_uint(x);
    u += 0x7fffu + ((u >> 16) & 1u);      // RNE
    return (unsigned short)(u >> 16);
}
__device__ inline float bf2f(unsigned short h){
    return __uint_as_float(((unsigned)h) << 16);
}

// ---------------------------------------------------------------------------
// prep_w: w fp32 [256][769] -> wprep bf16 fragment-ordered, K=768 linear.
// chunk = (ks*4+kq)*256 + o holds k = ks*32+kq*8+j (j=0..7 contiguous bf16)
// ---------------------------------------------------------------------------
__global__ __launch_bounds__(256) void prep_w(
    const float* __restrict__ w, unsigned short* __restrict__ wp)
{
    int idx = blockIdx.x * 256 + threadIdx.x;     // 196608 total
    int j  = idx & 7;
    int o  = (idx >> 3) & 255;
    int t2 = idx >> 11;                           // ks*4 + kq, 0..95
    int c  = (t2 >> 2) * 32 + (t2 & 3) * 8 + j;   // global k 0..767
    wp[idx] = f2bf(w[(size_t)o * KW_ + c]);
}

// ---------------------------------------------------------------------------
// conv kernel: fp32 -> bf16 fragment staging of f_s, sfb, AND f_w=attn*f_s.
// grid 512 = b(8) x pgrp(64); 256 thr; wave g stages k-chunk kq=g.
// Plane layout per matrix: [(b*8+ks8)*4+kq][pixel 4096] x 16B.
// f_s bf16 kept in registers (32 VGPR) -> f_w written without re-read.
// ---------------------------------------------------------------------------
__global__ __launch_bounds__(256) void conv_kernel(
    const float* __restrict__ f_s, const float* __restrict__ sfb,
    unsigned short* __restrict__ xf, unsigned short* __restrict__ xs,
    unsigned short* __restrict__ xw)
{
    __shared__ float red[4][64];
    __shared__ float attn_sm[64];
    int blk = blockIdx.x;
    int t = threadIdx.x, lane = t & 63, g = t >> 6;
    int b = blk >> 6;
    int p = (blk & 63) * 64 + lane;
    const float* fB = f_s + (size_t)b * C_IN * HW_ + p;
    const float* sB = sfb + (size_t)b * C_IN * HW_ + p;
    u16x8* XF = (u16x8*)xf;
    u16x8* XS = (u16x8*)xs;
    u16x8* XW = (u16x8*)xw;

    float ap = 0.f;
    u16x8 xfreg[8];
    float fv[8], sv[8], fv2[8], sv2[8];
    #pragma unroll
    for (int j = 0; j < 8; ++j) {
        fv[j] = fB[(size_t)(g * 8 + j) * HW_];
        sv[j] = sB[(size_t)(g * 8 + j) * HW_];
    }
    #pragma unroll
    for (int ks = 0; ks < 8; ++ks) {
        if (ks < 7) {
            #pragma unroll
            for (int j = 0; j < 8; ++j) {
                fv2[j] = fB[(size_t)((ks + 1) * 32 + g * 8 + j) * HW_];
                sv2[j] = sB[(size_t)((ks + 1) * 32 + g * 8 + j) * HW_];
            }
        }
        u16x8 pf, ps;
        #pragma unroll
        for (int j = 0; j < 8; ++j) {
            ap += fv[j] * sv[j];
            pf[j] = f2bf(fv[j]);
            ps[j] = f2bf(sv[j]);
        }
        int plane = (b * 8 + ks) * 4 + g;
        XF[(size_t)plane * HW_ + p] = pf;
        XS[(size_t)plane * HW_ + p] = ps;
        xfreg[ks] = pf;
        #pragma unroll
        for (int j = 0; j < 8; ++j) { fv[j] = fv2[j]; sv[j] = sv2[j]; }
    }
    red[g][lane] = ap;
    __syncthreads();
    if (t < 64) {
        float a = red[0][t] + red[1][t] + red[2][t] + red[3][t];
        attn_sm[t] = 1.f / (1.f + __expf(-a));
    }
    __syncthreads();
    float at = attn_sm[lane];
    #pragma unroll
    for (int ks = 0; ks < 8; ++ks) {
        u16x8 pw;
        #pragma unroll
        for (int j = 0; j < 8; ++j)
            pw[j] = f2bf(bf2f(xfreg[ks][j]) * at);
        XW[(size_t)((b * 8 + ks) * 4 + g) * HW_ + p] = pw;
    }
}

// ---------------------------------------------------------------------------
// dist kernel: packed-uint fg list, integer d2, 256 blocks x 512 thr.
// grid (8, 32): blockIdx.x = sample, blockIdx.y = 128-pixel tile.
// ---------------------------------------------------------------------------
__global__ __launch_bounds__(512) void dist_kernel(
    const float* __restrict__ mask, float* __restrict__ dist_raw,
    unsigned* __restrict__ dmax)
{
    __shared__ unsigned fg[4096];
    __shared__ int cnt;
    __shared__ float wmax[8];
    int b = blockIdx.x, tile = blockIdx.y;
    int t = threadIdx.x, lane = t & 63;
    if (t == 0) cnt = 0;
    __syncthreads();
    const float* mb = mask + (size_t)b * 65536;
    #pragma unroll
    for (int r = 0; r < 8; ++r) {
        int pp = r * 512 + t;
        int i = pp >> 6, j = pp & 63;
        bool pred = mb[i * 1024 + j * 4] > 0.5f;
        unsigned long long bal = __ballot(pred);
        int base = 0;
        if (lane == 0) base = atomicAdd(&cnt, __popcll(bal));
        base = __shfl(base, 0, 64);
        if (pred)
            fg[base + __popcll(bal & ((1ull << lane) - 1ull))] =
                (unsigned)((i << 8) | j);
    }
    __syncthreads();
    int nfg = cnt;
    int pix = tile * 128 + (t >> 2);
    int q = t & 3;
    int py = pix >> 6, px = pix & 63;
    int md = 0x7fffffff;
    #pragma unroll 4
    for (int it = q; it < nfg; it += 4) {
        unsigned e = fg[it];
        int dy = py - (int)(e >> 8);
        int dx = px - (int)(e & 255u);
        int d2 = dy * dy + dx * dx;
        md = min(md, d2);
    }
    md = min(md, __shfl_xor(md, 1, 64));
    md = min(md, __shfl_xor(md, 2, 64));
    float d = (nfg == 0) ? 1.0f : sqrtf((float)md);
    if (q == 0) dist_raw[b * HW_ + pix] = d;
    float mm = d;
    #pragma unroll
    for (int off = 1; off < 64; off <<= 1)
        mm = fmaxf(mm, __shfl_xor(mm, off, 64));
    if (lane == 0) wmax[t >> 6] = mm;
    __syncthreads();
    if (t == 0) {
        float M = wmax[0];
        #pragma unroll
        for (int i = 1; i < 8; ++i) M = fmaxf(M, wmax[i]);
        atomicMax(dmax + b, __float_as_uint(M));
    }
}

// ---------------------------------------------------------------------------
// Single MFMA GEMM: M=256, N=32768, K=768. Barrier/LDS-free.
// 128o x 128n per block, 4 waves (64o x 64n), acc[4][4] f32x4 (64 VGPR).
// Depth-1 register double-buffer on the 8 loads per K-step; 16 MFMA/step.
// Epilogue: + wd*dist, bf16 y store, BN partial stats.
// ---------------------------------------------------------------------------
__global__ __launch_bounds__(256) void gemm_kernel(
    const unsigned short* __restrict__ xf, const unsigned short* __restrict__ xs,
    const unsigned short* __restrict__ xw, const unsigned short* __restrict__ wprep,
    const float* __restrict__ w,
    const float* __restrict__ dist_raw, const unsigned* __restrict__ dmax,
    unsigned short* __restrict__ ybf,
    float* __restrict__ gsum, float* __restrict__ gsumsq)
{
    int bx = blockIdx.x;
    int ot = bx & 1, nt = bx >> 1;              // 2 x 256
    int oBase = ot * 128, nBase = nt * 128;     // 4096/128=32 tiles/sample exact
    int b = nBase >> 12, pBase = nBase & 4095;
    int t = threadIdx.x, lane = t & 63, g = t >> 6;
    int wo = g >> 1, wn = g & 1;
    int l15 = lane & 15, kq = lane >> 4;
    int oW = oBase + wo * 64;
    int pix0 = pBase + wn * 64 + l15;

    const bf16x8* WP  = (const bf16x8*)wprep;
    const bf16x8* XFp = (const bf16x8*)xf;
    const bf16x8* XSp = (const bf16x8*)xs;
    const bf16x8* XWp = (const bf16x8*)xw;

    f32x4 acc[4][4];
    #pragma unroll
    for (int fo = 0; fo < 4; ++fo)
        #pragma unroll
        for (int fn = 0; fn < 4; ++fn)
            acc[fo][fn] = (f32x4){0.f, 0.f, 0.f, 0.f};

    bf16x8 aC[4], xC[4];
    #pragma unroll
    for (int fn = 0; fn < 4; ++fn)
        xC[fn] = XFp[(size_t)((b * 8 + 0) * 4 + kq) * HW_ + pix0 + fn * 16];
    #pragma unroll
    for (int fo = 0; fo < 4; ++fo)
        aC[fo] = WP[(0 * 4 + kq) * 256 + oW + fo * 16 + l15];

    #pragma unroll
    for (int ks = 0; ks < 24; ++ks) {
        bf16x8 aN[4], xN[4];
        if (ks < 23) {
            int kn = ks + 1, mn = kn >> 3, k8 = kn & 7;
            const bf16x8* Xp = (mn == 0) ? XFp : ((mn == 1) ? XSp : XWp);
            #pragma unroll
            for (int fn = 0; fn < 4; ++fn)
                xN[fn] = Xp[(size_t)((b * 8 + k8) * 4 + kq) * HW_ + pix0 + fn * 16];
            #pragma unroll
            for (int fo = 0; fo < 4; ++fo)
                aN[fo] = WP[(kn * 4 + kq) * 256 + oW + fo * 16 + l15];
        }
        #pragma unroll
        for (int fo = 0; fo < 4; ++fo)
            #pragma unroll
            for (int fn = 0; fn < 4; ++fn)
                acc[fo][fn] = __builtin_amdgcn_mfma_f32_16x16x32_bf16(
                    aC[fo], xC[fn], acc[fo][fn], 0, 0, 0);
        if (ks < 23) {
            #pragma unroll
            for (int i = 0; i < 4; ++i) { aC[i] = aN[i]; xC[i] = xN[i]; }
        }
    }

    // ---- epilogue ----
    float dinv = 1.0f / (__uint_as_float(dmax[b]) + 1e-6f);
    const float* dR = dist_raw + b * HW_ + pBase + wn * 64;
    float dn[4];
    #pragma unroll
    for (int fn = 0; fn < 4; ++fn)
        dn[fn] = dR[fn * 16 + l15] * dinv;

    float s_acc[4][4], ss_acc[4][4];
    #pragma unroll
    for (int fo = 0; fo < 4; ++fo) {
        #pragma unroll
        for (int r = 0; r < 4; ++r) {
            int o = oW + fo * 16 + kq * 4 + r;
            float wd = w[(size_t)o * KW_ + 768];
            float s = 0.f, ss = 0.f;
            #pragma unroll
            for (int fn = 0; fn < 4; ++fn) {
                float v = acc[fo][fn][r] + wd * dn[fn];
                ybf[((size_t)(b * C_IN + o)) * HW_ + pBase + wn * 64 + fn * 16 + l15] = f2bf(v);
                s += v; ss += v * v;
            }
            s_acc[fo][r] = s; ss_acc[fo][r] = ss;
        }
    }
    #pragma unroll
    for (int m = 8; m; m >>= 1) {
        #pragma unroll
        for (int fo = 0; fo < 4; ++fo)
            #pragma unroll
            for (int r = 0; r < 4; ++r) {
                s_acc[fo][r]  += __shfl_xor(s_acc[fo][r],  m, 64);
                ss_acc[fo][r] += __shfl_xor(ss_acc[fo][r], m, 64);
            }
    }
    if (l15 == 0) {
        #pragma unroll
        for (int fo = 0; fo < 4; ++fo)
            #pragma unroll
            for (int r = 0; r < 4; ++r) {
                int o = oW + fo * 16 + kq * 4 + r;
                atomicAdd(&gsum[o],   s_acc[fo][r]);
                atomicAdd(&gsumsq[o], ss_acc[fo][r]);
            }
    }
}

// ---------------------------------------------------------------------------
// BN finalize + relu: read bf16 y, write fp32 out.
// ---------------------------------------------------------------------------
__global__ __launch_bounds__(256) void bn_kernel(
    const float* __restrict__ gsum, const float* __restrict__ gsumsq,
    const float* __restrict__ gamma, const float* __restrict__ beta,
    const unsigned short* __restrict__ ybf, float* __restrict__ out)
{
    int bo = blockIdx.x;
    int o = bo & 255;
    float mean = gsum[o] * (1.0f / NPIX_BN);
    float var  = gsumsq[o] * (1.0f / NPIX_BN) - mean * mean;
    float sc = gamma[o] * rsqrtf(var + 1e-5f);
    float sh = beta[o] - mean * sc;
    const u16x8* yp = (const u16x8*)(ybf + (size_t)bo * HW_);
    float4* op = (float4*)(out + (size_t)bo * HW_);
    int t = threadIdx.x;
    #pragma unroll
    for (int r = 0; r < 2; ++r) {
        u16x8 v = yp[r * 256 + t];
        float4 lo, hi;
        lo.x = fmaxf(bf2f(v[0]) * sc + sh, 0.f);
        lo.y = fmaxf(bf2f(v[1]) * sc + sh, 0.f);
        lo.z = fmaxf(bf2f(v[2]) * sc + sh, 0.f);
        lo.w = fmaxf(bf2f(v[3]) * sc + sh, 0.f);
        hi.x = fmaxf(bf2f(v[4]) * sc + sh, 0.f);
        hi.y = fmaxf(bf2f(v[5]) * sc + sh, 0.f);
        hi.z = fmaxf(bf2f(v[6]) * sc + sh, 0.f);
        hi.w = fmaxf(bf2f(v[7]) * sc + sh, 0.f);
        op[(r * 256 + t) * 2]     = lo;
        op[(r * 256 + t) * 2 + 1] = hi;
    }
}

// ---------------------------------------------------------------------------
// ws layout (float units):
//   [0,     32768)   dist_raw
//   [32768, 32776)   dmax (uint)
//   [32784, 33040)   gsum
//   [33040, 33296)   gsumsq
//   [33296, 131600)  wprep (196608 ushort)
//   [131600, ...)    staging:
//     P1 (ws >= ~68MB): XF | XS | XW | ybf (4 x 4194304 floats)
//     P2 (else):        XF,XS in d_out (exact 33.5MB fit, consumed by gemm
//                       before bn rewrites d_out); XW | ybf in ws.
// ---------------------------------------------------------------------------
extern "C" void kernel_launch(void* const* d_in, const int* in_sizes, int n_in,
                              void* d_out, int out_size, void* d_ws, size_t ws_size,
                              hipStream_t stream)
{
    const float* f_s   = (const float*)d_in[0];
    const float* sfb   = (const float*)d_in[1];
    const float* mask  = (const float*)d_in[2];
    const float* w     = (const float*)d_in[3];
    const float* gamma = (const float*)d_in[4];
    const float* beta  = (const float*)d_in[5];
    float* out = (float*)d_out;
    float* ws  = (float*)d_ws;

    float*          dist_raw = ws;
    unsigned*       dmax     = (unsigned*)(ws + 32768);
    float*          gsum     = ws + 32784;
    float*          gsumsq   = ws + 33040;
    unsigned short* wprep    = (unsigned short*)(ws + 33296);

    const size_t P1_need = ((size_t)131600 + 4 * 4194304) * 4;  // ~67.6 MB
    unsigned short *xf, *xs, *xw, *ybf;
    if (ws_size >= P1_need) {
        xf  = (unsigned short*)(ws + 131600);
        xs  = (unsigned short*)(ws + 131600 + 1 * (size_t)4194304);
        xw  = (unsigned short*)(ws + 131600 + 2 * (size_t)4194304);
        ybf = (unsigned short*)(ws + 131600 + 3 * (size_t)4194304);
    } else {
        xf  = (unsigned short*)d_out;
        xs  = ((unsigned short*)d_out) + 8388608;
        xw  = (unsigned short*)(ws + 131600);
        ybf = (unsigned short*)(ws + 131600 + (size_t)4194304);
    }

    hipMemsetAsync(ws + 32768, 0, (33296 - 32768) * 4, stream);

    prep_w<<<768, 256, 0, stream>>>(w, wprep);
    conv_kernel<<<512, 256, 0, stream>>>(f_s, sfb, xf, xs, xw);
    dist_kernel<<<dim3(8, 32), 512, 0, stream>>>(mask, dist_raw, dmax);
    gemm_kernel<<<512, 256, 0, stream>>>(xf, xs, xw, wprep, w, dist_raw,
                                         dmax, ybf, gsum, gsumsq);
    bn_kernel<<<2048, 256, 0, stream>>>(gsum, gsumsq, gamma, beta, ybf, out);
}